// Round 1
// baseline (2307.514 us; speedup 1.0000x reference)
//
#include <hip/hip_runtime.h>
#include <hip/hip_bf16.h>

// Problem constants
#define B_   2048   // batch
#define E_   512    // embedding / hidden
#define S_   64     // sequence length
#define K_   1024   // fused GEMM K = E (x part) + E (h part)
#define NG   2048   // 4*E gate rows

#define BM 128
#define BN 128
#define BK 32

typedef __attribute__((ext_vector_type(8))) short  bfrag8;
typedef __attribute__((ext_vector_type(4))) float  f32x4;

__device__ __forceinline__ void gload16(const void* g, void* l) {
  __builtin_amdgcn_global_load_lds(
      (const __attribute__((address_space(1))) unsigned int*)g,
      (__attribute__((address_space(3))) unsigned int*)l,
      16, 0, 0);
}

__device__ __forceinline__ float sigm(float x)      { return 1.f / (1.f + __expf(-x)); }
__device__ __forceinline__ float tanh_fast(float x) { return 2.f / (1.f + __expf(-2.f * x)) - 1.f; }

// Build permuted bf16 weight matrix Wp[2048][1024] and permuted bias.
// Permuted row p (block te = p>>7 owns rows [te*128, te*128+128)):
//   local col c = p&127 = g*32 + j  ->  original gate row n = g*512 + te*32 + j
//   Wp[p][0:512]   = W_ih[n][:]   (bf16)
//   Wp[p][512:1024]= W_hh[n][:]   (bf16)
__global__ __launch_bounds__(256) void prep_weights(
    const float* __restrict__ Wih, const float* __restrict__ Whh,
    const float* __restrict__ bih, const float* __restrict__ bhh,
    __hip_bfloat16* __restrict__ Wp, float* __restrict__ biasP)
{
  int p  = blockIdx.x;
  int te = p >> 7;
  int g  = (p >> 5) & 3;
  int j  = p & 31;
  int n  = g * E_ + te * 32 + j;
  const float* s0 = Wih + (size_t)n * E_;
  const float* s1 = Whh + (size_t)n * E_;
  __hip_bfloat16* dst = Wp + (size_t)p * K_;
  for (int k = threadIdx.x; k < E_; k += 256) {
    dst[k]       = __float2bfloat16(s0[k]);
    dst[E_ + k]  = __float2bfloat16(s1[k]);
  }
  if (threadIdx.x == 0) biasP[p] = bih[n] + bhh[n];
}

// c = 0; A0[b][0:512] = bf16(emb[x[b][0]]); A0[b][512:1024] = 0 (h0 = 0)
__global__ __launch_bounds__(256) void init_state(
    const int* __restrict__ x, const float* __restrict__ emb,
    float* __restrict__ c, __hip_bfloat16* __restrict__ A0)
{
  int b  = blockIdx.x;
  int xi = x[(size_t)b * S_ + 0];
  const float* e = emb + (size_t)xi * E_;
  __hip_bfloat16* a = A0 + (size_t)b * K_;
  float* cr = c + (size_t)b * E_;
  for (int k = threadIdx.x; k < E_; k += 256) {
    a[k]       = __float2bfloat16(e[k]);
    a[E_ + k]  = __float2bfloat16(0.f);
    cr[k]      = 0.f;
  }
}

// One fused LSTM timestep:
//   gates[b][p] = sum_k Acur[b][k] * Wp[p][k]   (K=1024: [xt | h_prev])
//   cell update + write next step's A (emb gather for t+1 and bf16 h)
__global__ __launch_bounds__(256) void lstm_step(
    const __hip_bfloat16* __restrict__ Acur,   // [2048][1024] bf16
    __hip_bfloat16* __restrict__ Anext,        // [2048][1024] bf16
    const __hip_bfloat16* __restrict__ Wp,     // [2048][1024] bf16 (permuted rows)
    const float* __restrict__ biasP,           // [2048] permuted
    float* __restrict__ c,                     // [2048][512] fp32
    const int* __restrict__ x,                 // [2048][64] int32
    const float* __restrict__ emb,             // [32000][512] fp32
    float* __restrict__ out,                   // [2048][512] fp32 (last step)
    int t)
{
  __shared__ __hip_bfloat16 As[2][BM * BK];   // 8 KB x2
  __shared__ __hip_bfloat16 Bs[2][BN * BK];   // 8 KB x2
  __shared__ float gl[BM][BN + 4];            // 66 KB gates tile
  __shared__ float biasS[BN];

  const int tid = threadIdx.x;
  const int tm  = blockIdx.x & 15;   // row tile
  const int te  = blockIdx.x >> 4;   // permuted col tile (e block)
  const int w   = tid >> 6;
  const int l   = tid & 63;
  const int wr  = w >> 1;
  const int wc  = w & 1;

  if (tid < BN) biasS[tid] = biasP[te * BN + tid];

  const int arow0 = tm * BM;
  const int brow0 = te * BN;

  int aoff[4], boff[4];
#pragma unroll
  for (int m = 0; m < 4; ++m)
    aoff[m] = (wr * 64 + m * 16 + (l & 15)) * BK + ((l >> 4) << 3);
#pragma unroll
  for (int n = 0; n < 4; ++n)
    boff[n] = (wc * 64 + n * 16 + (l & 15)) * BK + ((l >> 4) << 3);

  f32x4 acc[4][4];
#pragma unroll
  for (int m = 0; m < 4; ++m)
#pragma unroll
    for (int n = 0; n < 4; ++n)
      acc[m][n] = (f32x4){0.f, 0.f, 0.f, 0.f};

  auto stage = [&](int kt, int buf) {
    const int k0 = kt * BK;
#pragma unroll
    for (int it = 0; it < 2; ++it) {
      int ch  = it * 256 + tid;
      int row = ch >> 2;            // 0..127
      int ko  = (ch & 3) << 3;      // 0,8,16,24 (bf16 elems)
      gload16(Acur + (size_t)(arow0 + row) * K_ + k0 + ko, &As[buf][ch * 8]);
      gload16(Wp   + (size_t)(brow0 + row) * K_ + k0 + ko, &Bs[buf][ch * 8]);
    }
  };

  stage(0, 0);
  int cur = 0;
#pragma unroll 1
  for (int kt = 0; kt < K_ / BK; ++kt) {
    __syncthreads();                       // staging of `cur` complete; prev reads done
    if (kt + 1 < K_ / BK) stage(kt + 1, cur ^ 1);
    bfrag8 af[4], bfr[4];
#pragma unroll
    for (int m = 0; m < 4; ++m) af[m]  = *(const bfrag8*)&As[cur][aoff[m]];
#pragma unroll
    for (int n = 0; n < 4; ++n) bfr[n] = *(const bfrag8*)&Bs[cur][boff[n]];
#pragma unroll
    for (int m = 0; m < 4; ++m)
#pragma unroll
      for (int n = 0; n < 4; ++n)
        acc[m][n] = __builtin_amdgcn_mfma_f32_16x16x32_bf16(af[m], bfr[n], acc[m][n], 0, 0, 0);
    cur ^= 1;
  }

  // ---- epilogue: gates -> LDS (with bias), then cell update ----
#pragma unroll
  for (int m = 0; m < 4; ++m) {
    int row0 = wr * 64 + m * 16 + ((l >> 4) << 2);
#pragma unroll
    for (int n = 0; n < 4; ++n) {
      int col  = wc * 64 + n * 16 + (l & 15);
      float bv = biasS[col];
#pragma unroll
      for (int r = 0; r < 4; ++r)
        gl[row0 + r][col] = acc[m][n][r] + bv;
    }
  }
  __syncthreads();

  const int j  = tid & 31;
  const int rs = tid >> 5;
  const int e  = te * 32 + j;
  const bool last = (t == S_ - 1);
#pragma unroll
  for (int it = 0; it < 16; ++it) {
    int r  = rs + it * 8;
    int gb = tm * BM + r;
    float iv = gl[r][j];
    float fv = gl[r][32 + j];
    float gv = gl[r][64 + j];
    float ov = gl[r][96 + j];
    size_t cidx = (size_t)gb * E_ + e;
    float cold = c[cidx];
    float ig = sigm(iv), fg = sigm(fv), gg = tanh_fast(gv), og = sigm(ov);
    float cn = fg * cold + ig * gg;
    c[cidx] = cn;
    float h = og * tanh_fast(cn);
    if (last) {
      out[cidx] = h;
    } else {
      Anext[(size_t)gb * K_ + E_ + e] = __float2bfloat16(h);
      int xi = x[(size_t)gb * S_ + t + 1];
      Anext[(size_t)gb * K_ + e] = __float2bfloat16(emb[(size_t)xi * E_ + e]);
    }
  }
}

extern "C" void kernel_launch(void* const* d_in, const int* in_sizes, int n_in,
                              void* d_out, int out_size, void* d_ws, size_t ws_size,
                              hipStream_t stream) {
  const int*   x   = (const int*)d_in[0];
  const float* emb = (const float*)d_in[1];
  const float* Wih = (const float*)d_in[2];
  const float* Whh = (const float*)d_in[3];
  const float* bih = (const float*)d_in[4];
  const float* bhh = (const float*)d_in[5];
  float* out = (float*)d_out;
  (void)in_sizes; (void)n_in; (void)out_size; (void)ws_size;

  char* p = (char*)d_ws;
  __hip_bfloat16* Wp    = (__hip_bfloat16*)p;  p += (size_t)NG * K_ * 2;  // 4 MB
  float*          biasP = (float*)p;           p += (size_t)NG * 4;       // 8 KB
  float*          c     = (float*)p;           p += (size_t)B_ * E_ * 4;  // 4 MB
  __hip_bfloat16* A0    = (__hip_bfloat16*)p;  p += (size_t)B_ * K_ * 2;  // 4 MB
  __hip_bfloat16* A1    = (__hip_bfloat16*)p;  p += (size_t)B_ * K_ * 2;  // 4 MB

  prep_weights<<<NG, 256, 0, stream>>>(Wih, Whh, bih, bhh, Wp, biasP);
  init_state<<<B_, 256, 0, stream>>>(x, emb, c, A0);
  for (int t = 0; t < S_; ++t) {
    __hip_bfloat16* Ac = (t & 1) ? A1 : A0;
    __hip_bfloat16* An = (t & 1) ? A0 : A1;
    lstm_step<<<256, 256, 0, stream>>>(Ac, An, Wp, biasP, c, x, emb, out, t);
  }
}

// Round 2
// 2214.872 us; speedup vs baseline: 1.0418x; 1.0418x over previous
//
#include <hip/hip_runtime.h>
#include <hip/hip_bf16.h>

// Problem constants
#define B_   2048   // batch
#define E_   512    // embedding / hidden
#define S_   64     // sequence length
#define K_   1024   // fused GEMM K = E (x part) + E (h part)
#define NG   2048   // 4*E gate rows

#define BM 64
#define BN 128
#define BK 32

typedef __attribute__((ext_vector_type(8))) short  bfrag8;
typedef __attribute__((ext_vector_type(4))) float  f32x4;

__device__ __forceinline__ void gload16(const void* g, void* l) {
  __builtin_amdgcn_global_load_lds(
      (const __attribute__((address_space(1))) unsigned int*)g,
      (__attribute__((address_space(3))) unsigned int*)l,
      16, 0, 0);
}

__device__ __forceinline__ float sigm(float x)      { return 1.f / (1.f + __expf(-x)); }
__device__ __forceinline__ float tanh_fast(float x) { return 2.f / (1.f + __expf(-2.f * x)) - 1.f; }

// Gate-interleaved permutation.
// Permuted row p: te = p>>7 (16 col-tiles of 128), c = p&127 = hi*64 + g*16 + q
//   (hi = wave-col half, g = gate, q = lane col)
//   e = te*32 + hi*16 + q ; original gate row n = g*512 + e
// Wp[p][0:512] = W_ih[n][:], Wp[p][512:1024] = W_hh[n][:]  (bf16)
__global__ __launch_bounds__(256) void prep_weights(
    const float* __restrict__ Wih, const float* __restrict__ Whh,
    const float* __restrict__ bih, const float* __restrict__ bhh,
    __hip_bfloat16* __restrict__ Wp, float* __restrict__ biasP)
{
  int p  = blockIdx.x;
  int te = p >> 7;
  int c  = p & 127;
  int hi = (c >> 6) & 1;
  int g  = (c >> 4) & 3;
  int q  = c & 15;
  int e  = te * 32 + hi * 16 + q;
  int n  = g * E_ + e;
  const float* s0 = Wih + (size_t)n * E_;
  const float* s1 = Whh + (size_t)n * E_;
  __hip_bfloat16* dst = Wp + (size_t)p * K_;
  for (int k = threadIdx.x; k < E_; k += 256) {
    dst[k]       = __float2bfloat16(s0[k]);
    dst[E_ + k]  = __float2bfloat16(s1[k]);
  }
  if (threadIdx.x == 0) biasP[p] = bih[n] + bhh[n];
}

// c = 0; A0[b][0:512] = bf16(emb[x[b][0]]); A0[b][512:1024] = 0 (h0 = 0)
__global__ __launch_bounds__(256) void init_state(
    const int* __restrict__ x, const float* __restrict__ emb,
    float* __restrict__ c, __hip_bfloat16* __restrict__ A0)
{
  int b  = blockIdx.x;
  int xi = x[(size_t)b * S_ + 0];
  const float* e = emb + (size_t)xi * E_;
  __hip_bfloat16* a = A0 + (size_t)b * K_;
  float* cr = c + (size_t)b * E_;
  for (int k = threadIdx.x; k < E_; k += 256) {
    a[k]       = __float2bfloat16(e[k]);
    a[E_ + k]  = __float2bfloat16(0.f);
    cr[k]      = 0.f;
  }
}

// One fused LSTM timestep. 2 waves/block; wave = 64 rows x 64 cols (acc[4][4]).
// Gate-interleaved W rows -> all 4 gates of a (b,e) pair live in one thread.
__global__ __launch_bounds__(128) void lstm_step(
    const __hip_bfloat16* __restrict__ Acur,   // [2048][1024] bf16
    __hip_bfloat16* __restrict__ Anext,        // [2048][1024] bf16
    const __hip_bfloat16* __restrict__ Wp,     // [2048][1024] bf16 (permuted rows)
    const float* __restrict__ biasP,           // [2048] permuted
    float* __restrict__ c,                     // [2048][512] fp32
    const int* __restrict__ x,                 // [2048][64] int32
    const float* __restrict__ emb,             // [32000][512] fp32
    float* __restrict__ out,                   // [2048][512] fp32 (last step)
    int t)
{
  __shared__ __hip_bfloat16 As[2][BM * BK];   // 4 KB x2
  __shared__ __hip_bfloat16 Bs[2][BN * BK];   // 8 KB x2

  const int tid = threadIdx.x;
  // XCD-chunked 2D swizzle: XCD x7 owns tm-half (x7&1) x te-quarter (x7>>1).
  // Per-XCD slices: A 2 MB, Wp 1 MB (Wp slice is step-invariant -> L2-resident).
  const int x7 = blockIdx.x & 7;
  const int i  = blockIdx.x >> 3;              // 0..63
  const int tm = (x7 & 1) * 16 + (i & 15);     // 0..31 (row tile of 64)
  const int te = (x7 >> 1) * 4 + (i >> 4);     // 0..15 (col tile of 128)

  const int wc = tid >> 6;                     // wave 0..1 = col half
  const int l  = tid & 63;
  const int lq = l & 15;
  const int lh = l >> 4;

  const int arow0 = tm * BM;
  const int brow0 = te * BN;

  // bias: 4 gates for this thread's e-column
  float bg[4];
#pragma unroll
  for (int n = 0; n < 4; ++n)
    bg[n] = biasP[te * 128 + wc * 64 + n * 16 + lq];

  int aoff[4], boff[4];
#pragma unroll
  for (int m = 0; m < 4; ++m)
    aoff[m] = (m * 16 + lq) * BK + (lh << 3);
#pragma unroll
  for (int n = 0; n < 4; ++n)
    boff[n] = (wc * 64 + n * 16 + lq) * BK + (lh << 3);

  f32x4 acc[4][4];
#pragma unroll
  for (int m = 0; m < 4; ++m)
#pragma unroll
    for (int n = 0; n < 4; ++n)
      acc[m][n] = (f32x4){0.f, 0.f, 0.f, 0.f};

  auto stage = [&](int kt, int buf) {
    const int k0 = kt * BK;
    // A tile: 64 rows x 64 B = 256 chunks; 2 per thread
#pragma unroll
    for (int it = 0; it < 2; ++it) {
      int ch  = it * 128 + tid;
      int row = ch >> 2;
      int ko  = (ch & 3) << 3;
      gload16(Acur + (size_t)(arow0 + row) * K_ + k0 + ko, &As[buf][ch * 8]);
    }
    // B tile: 128 rows x 64 B = 512 chunks; 4 per thread
#pragma unroll
    for (int it = 0; it < 4; ++it) {
      int ch  = it * 128 + tid;
      int row = ch >> 2;
      int ko  = (ch & 3) << 3;
      gload16(Wp + (size_t)(brow0 + row) * K_ + k0 + ko, &Bs[buf][ch * 8]);
    }
  };

  stage(0, 0);
  int cur = 0;
#pragma unroll 1
  for (int kt = 0; kt < K_ / BK; ++kt) {
    __syncthreads();                       // staging of `cur` complete; prev reads done
    if (kt + 1 < K_ / BK) stage(kt + 1, cur ^ 1);
    bfrag8 af[4], bfr[4];
#pragma unroll
    for (int m = 0; m < 4; ++m) af[m]  = *(const bfrag8*)&As[cur][aoff[m]];
#pragma unroll
    for (int n = 0; n < 4; ++n) bfr[n] = *(const bfrag8*)&Bs[cur][boff[n]];
#pragma unroll
    for (int m = 0; m < 4; ++m)
#pragma unroll
      for (int n = 0; n < 4; ++n)
        acc[m][n] = __builtin_amdgcn_mfma_f32_16x16x32_bf16(af[m], bfr[n], acc[m][n], 0, 0, 0);
    cur ^= 1;
  }

  // ---- register epilogue: thread holds gates i,f,g,o (n=0..3) for 16 (b,e) ----
  const int e    = te * 32 + wc * 16 + lq;
  const bool last = (t == S_ - 1);
#pragma unroll
  for (int m = 0; m < 4; ++m) {
#pragma unroll
    for (int r = 0; r < 4; ++r) {
      int b = tm * BM + m * 16 + lh * 4 + r;
      float iv = acc[m][0][r] + bg[0];
      float fv = acc[m][1][r] + bg[1];
      float gv = acc[m][2][r] + bg[2];
      float ov = acc[m][3][r] + bg[3];
      size_t cidx = (size_t)b * E_ + e;
      float cold = c[cidx];
      float ig = sigm(iv), fg = sigm(fv), gg = tanh_fast(gv), og = sigm(ov);
      float cn = fg * cold + ig * gg;
      c[cidx] = cn;
      float h = og * tanh_fast(cn);
      if (last) {
        out[cidx] = h;
      } else {
        Anext[(size_t)b * K_ + E_ + e] = __float2bfloat16(h);
        int xi = x[(size_t)b * S_ + t + 1];
        Anext[(size_t)b * K_ + e] = __float2bfloat16(emb[(size_t)xi * E_ + e]);
      }
    }
  }
}

extern "C" void kernel_launch(void* const* d_in, const int* in_sizes, int n_in,
                              void* d_out, int out_size, void* d_ws, size_t ws_size,
                              hipStream_t stream) {
  const int*   x   = (const int*)d_in[0];
  const float* emb = (const float*)d_in[1];
  const float* Wih = (const float*)d_in[2];
  const float* Whh = (const float*)d_in[3];
  const float* bih = (const float*)d_in[4];
  const float* bhh = (const float*)d_in[5];
  float* out = (float*)d_out;
  (void)in_sizes; (void)n_in; (void)out_size; (void)ws_size;

  char* p = (char*)d_ws;
  __hip_bfloat16* Wp    = (__hip_bfloat16*)p;  p += (size_t)NG * K_ * 2;  // 4 MB
  float*          biasP = (float*)p;           p += (size_t)NG * 4;       // 8 KB
  float*          c     = (float*)p;           p += (size_t)B_ * E_ * 4;  // 4 MB
  __hip_bfloat16* A0    = (__hip_bfloat16*)p;  p += (size_t)B_ * K_ * 2;  // 4 MB
  __hip_bfloat16* A1    = (__hip_bfloat16*)p;  p += (size_t)B_ * K_ * 2;  // 4 MB

  prep_weights<<<NG, 256, 0, stream>>>(Wih, Whh, bih, bhh, Wp, biasP);
  init_state<<<B_, 256, 0, stream>>>(x, emb, c, A0);
  for (int t = 0; t < S_; ++t) {
    __hip_bfloat16* Ac = (t & 1) ? A1 : A0;
    __hip_bfloat16* An = (t & 1) ? A0 : A1;
    lstm_step<<<512, 128, 0, stream>>>(Ac, An, Wp, biasP, c, x, emb, out, t);
  }
}

// Round 4
// 1600.831 us; speedup vs baseline: 1.4414x; 1.3836x over previous
//
#include <hip/hip_runtime.h>
#include <hip/hip_bf16.h>

// Problem constants
#define B_   2048   // batch
#define E_   512    // embedding / hidden
#define S_   64     // sequence length
#define K_   1024   // fused GEMM K = E (x part) + E (h part)
#define NG   2048   // 4*E gate rows

#define BM 64
#define BN 128
#define BK 32
#define NKT (K_/BK)   // 32 K-tiles
#define ND  5         // LDS ring depth (prefetch distance 4)

typedef __attribute__((ext_vector_type(8))) short  bfrag8;
typedef __attribute__((ext_vector_type(4))) float  f32x4;

#define WAITVM(N) asm volatile("s_waitcnt vmcnt(" #N ")" ::: "memory")

__device__ __forceinline__ void gload16(const void* g, void* l) {
  __builtin_amdgcn_global_load_lds(
      (const __attribute__((address_space(1))) unsigned int*)g,
      (__attribute__((address_space(3))) unsigned int*)l,
      16, 0, 0);
}

__device__ __forceinline__ float sigm(float x)      { return 1.f / (1.f + __expf(-x)); }
__device__ __forceinline__ float tanh_fast(float x) { return 2.f / (1.f + __expf(-2.f * x)) - 1.f; }

// Gate-interleaved permutation (verified by absmax pass in rounds 1-2).
// Permuted row p: te = p>>7, c = p&127 = hi*64 + g*16 + q
//   e = te*32 + hi*16 + q ; original gate row n = g*512 + e
// Wp[p][0:512] = W_ih[n][:], Wp[p][512:1024] = W_hh[n][:]  (bf16)
__global__ __launch_bounds__(256) void prep_weights(
    const float* __restrict__ Wih, const float* __restrict__ Whh,
    const float* __restrict__ bih, const float* __restrict__ bhh,
    __hip_bfloat16* __restrict__ Wp, float* __restrict__ biasP)
{
  int p  = blockIdx.x;
  int te = p >> 7;
  int c  = p & 127;
  int hi = (c >> 6) & 1;
  int g  = (c >> 4) & 3;
  int q  = c & 15;
  int e  = te * 32 + hi * 16 + q;
  int n  = g * E_ + e;
  const float* s0 = Wih + (size_t)n * E_;
  const float* s1 = Whh + (size_t)n * E_;
  __hip_bfloat16* dst = Wp + (size_t)p * K_;
  for (int k = threadIdx.x; k < E_; k += 256) {
    dst[k]       = __float2bfloat16(s0[k]);
    dst[E_ + k]  = __float2bfloat16(s1[k]);
  }
  if (threadIdx.x == 0) biasP[p] = bih[n] + bhh[n];
}

// c = 0; A0[b][0:512] = bf16(emb[x[b][0]]); A0[b][512:1024] = 0 (h0 = 0)
__global__ __launch_bounds__(256) void init_state(
    const int* __restrict__ x, const float* __restrict__ emb,
    float* __restrict__ c, __hip_bfloat16* __restrict__ A0)
{
  int b  = blockIdx.x;
  int xi = x[(size_t)b * S_ + 0];
  const float* e = emb + (size_t)xi * E_;
  __hip_bfloat16* a = A0 + (size_t)b * K_;
  float* cr = c + (size_t)b * E_;
  for (int k = threadIdx.x; k < E_; k += 256) {
    a[k]       = __float2bfloat16(e[k]);
    a[E_ + k]  = __float2bfloat16(0.f);
    cr[k]      = 0.f;
  }
}

// One fused LSTM timestep. 2 waves/block, wave = 64x64 (acc[4][4]).
// Counted-vmcnt 5-deep pipeline; XOR-swizzled LDS; prefetched epilogue operands.
__global__ __launch_bounds__(128) void lstm_step(
    const __hip_bfloat16* __restrict__ Acur,   // [2048][1024] bf16
    __hip_bfloat16* __restrict__ Anext,        // [2048][1024] bf16
    const __hip_bfloat16* __restrict__ Wp,     // [2048][1024] bf16 (permuted)
    const float* __restrict__ biasP,           // [2048] permuted
    float* __restrict__ c,                     // [2048][512] fp32
    const int* __restrict__ x,                 // [2048][64] int32
    const float* __restrict__ emb,             // [32000][512] fp32
    float* __restrict__ out,                   // [2048][512] fp32
    int t)
{
  __shared__ __hip_bfloat16 As[ND][BM * BK];   // 5 x 4 KB
  __shared__ __hip_bfloat16 Bs[ND][BN * BK];   // 5 x 8 KB

  const int tid = threadIdx.x;
  // XCD-chunked 2D swizzle (per-XCD: 16 tm x 4 te; Wp slice 1 MB step-invariant)
  const int x7 = blockIdx.x & 7;
  const int i  = blockIdx.x >> 3;
  const int tm = (x7 & 1) * 16 + (i & 15);
  const int te = (x7 >> 1) * 4 + (i >> 4);

  const int wc = tid >> 6;
  const int l  = tid & 63;
  const int lq = l & 15;
  const int lh = l >> 4;

  const int arow0 = tm * BM;
  const int brow0 = te * BN;

  // ---- prefetches (issued before the GEMM pipeline) ----
  float bg[4];
#pragma unroll
  for (int n = 0; n < 4; ++n)
    bg[n] = biasP[te * 128 + wc * 64 + n * 16 + lq];

  const int e = te * 32 + wc * 16 + lq;
  float cold[4][4];
  int   xiv[4][4];
  const int tn = (t < S_ - 1) ? t + 1 : S_ - 1;
#pragma unroll
  for (int m = 0; m < 4; ++m)
#pragma unroll
    for (int r = 0; r < 4; ++r) {
      int b = tm * BM + m * 16 + lh * 4 + r;
      cold[m][r] = c[(size_t)b * E_ + e];
      xiv[m][r]  = x[(size_t)b * S_ + tn];
    }
  __builtin_amdgcn_sched_barrier(0);

  auto stage = [&](int kt, int buf) {
    const int k0 = kt * BK;
#pragma unroll
    for (int it = 0; it < 2; ++it) {
      int ch  = it * 128 + tid;
      int row = ch >> 2;
      int ks  = (((ch & 3) ^ (row & 3)) << 3);   // inverse-swizzled source k
      gload16(Acur + (size_t)(arow0 + row) * K_ + k0 + ks, &As[buf][ch * 8]);
    }
#pragma unroll
    for (int it = 0; it < 4; ++it) {
      int ch  = it * 128 + tid;
      int row = ch >> 2;
      int ks  = (((ch & 3) ^ (row & 3)) << 3);
      gload16(Wp + (size_t)(brow0 + row) * K_ + k0 + ks, &Bs[buf][ch * 8]);
    }
  };

  stage(0, 0);                                  // 6 loads
  __builtin_amdgcn_sched_barrier(0);
  float ev[4][4];                                // emb gather (waits xi: vmcnt leaves s0)
#pragma unroll
  for (int m = 0; m < 4; ++m)
#pragma unroll
    for (int r = 0; r < 4; ++r)
      ev[m][r] = emb[(size_t)xiv[m][r] * E_ + e];   // 16 loads
  __builtin_amdgcn_sched_barrier(0);
  stage(1, 1); stage(2, 2); stage(3, 3);        // 18 loads
  __builtin_amdgcn_sched_barrier(0);

  // ---- fragment offsets (swizzled reads; residual 4-way conflict) ----
  const int xo = (lh ^ (lq & 3)) << 3;
  int aoff[4], boff[4];
#pragma unroll
  for (int m = 0; m < 4; ++m) aoff[m] = (m * 16 + lq) * BK + xo;
#pragma unroll
  for (int n = 0; n < 4; ++n) boff[n] = (wc * 64 + n * 16 + lq) * BK + xo;

  f32x4 acc[4][4];
#pragma unroll
  for (int m = 0; m < 4; ++m)
#pragma unroll
    for (int n = 0; n < 4; ++n)
      acc[m][n] = (f32x4){0.f, 0.f, 0.f, 0.f};

  auto mfma_iter = [&](int rb) {
    bfrag8 af[4], bfr[4];
    const __hip_bfloat16* Ab = &As[rb][0];
    const __hip_bfloat16* Bb = &Bs[rb][0];
#pragma unroll
    for (int m = 0; m < 4; ++m) af[m]  = *(const bfrag8*)(Ab + aoff[m]);
#pragma unroll
    for (int n = 0; n < 4; ++n) bfr[n] = *(const bfrag8*)(Bb + boff[n]);
    __builtin_amdgcn_s_setprio(1);
#pragma unroll
    for (int m = 0; m < 4; ++m)
#pragma unroll
      for (int n = 0; n < 4; ++n)
        acc[m][n] = __builtin_amdgcn_mfma_f32_16x16x32_bf16(af[m], bfr[n], acc[m][n], 0, 0, 0);
    __builtin_amdgcn_s_setprio(0);
  };

  // ---- counted-vmcnt pipeline ----
  // queue at kt=0: [s0(6), emb(16), s1, s2, s3]=40 -> keep 34 => s0 done
  WAITVM(34); __builtin_amdgcn_s_barrier(); __builtin_amdgcn_sched_barrier(0);
  stage(4, 4);
  mfma_iter(0);

  int rb = 1, sb = 0;
#pragma unroll 1
  for (int kt = 1; kt <= 27; ++kt) {
    WAITVM(18); __builtin_amdgcn_s_barrier(); __builtin_amdgcn_sched_barrier(0);
    stage(kt + 4, sb);
    mfma_iter(rb);
    rb = (rb == ND - 1) ? 0 : rb + 1;
    sb = (sb == ND - 1) ? 0 : sb + 1;
  }
  // tail: kt = 28..31 read bufs 3,4,0,1; no more stages
  WAITVM(18); __builtin_amdgcn_s_barrier(); __builtin_amdgcn_sched_barrier(0); mfma_iter(3);
  WAITVM(12); __builtin_amdgcn_s_barrier(); __builtin_amdgcn_sched_barrier(0); mfma_iter(4);
  WAITVM(6);  __builtin_amdgcn_s_barrier(); __builtin_amdgcn_sched_barrier(0); mfma_iter(0);
  WAITVM(0);  __builtin_amdgcn_s_barrier(); __builtin_amdgcn_sched_barrier(0); mfma_iter(1);

  // ---- register epilogue ----
  const bool last = (t == S_ - 1);
#pragma unroll
  for (int m = 0; m < 4; ++m) {
#pragma unroll
    for (int r = 0; r < 4; ++r) {
      int b = tm * BM + m * 16 + lh * 4 + r;
      float iv = acc[m][0][r] + bg[0];
      float fv = acc[m][1][r] + bg[1];
      float gv = acc[m][2][r] + bg[2];
      float ov = acc[m][3][r] + bg[3];
      size_t cidx = (size_t)b * E_ + e;
      float ig = sigm(iv), fg = sigm(fv), gg = tanh_fast(gv), og = sigm(ov);
      float cn = fg * cold[m][r] + ig * gg;
      c[cidx] = cn;
      float h = og * tanh_fast(cn);
      if (last) {
        out[cidx] = h;
      } else {
        Anext[(size_t)b * K_ + E_ + e] = __float2bfloat16(h);
        Anext[(size_t)b * K_ + e]      = __float2bfloat16(ev[m][r]);
      }
    }
  }
}

extern "C" void kernel_launch(void* const* d_in, const int* in_sizes, int n_in,
                              void* d_out, int out_size, void* d_ws, size_t ws_size,
                              hipStream_t stream) {
  const int*   x   = (const int*)d_in[0];
  const float* emb = (const float*)d_in[1];
  const float* Wih = (const float*)d_in[2];
  const float* Whh = (const float*)d_in[3];
  const float* bih = (const float*)d_in[4];
  const float* bhh = (const float*)d_in[5];
  float* out = (float*)d_out;
  (void)in_sizes; (void)n_in; (void)out_size; (void)ws_size;

  char* p = (char*)d_ws;
  __hip_bfloat16* Wp    = (__hip_bfloat16*)p;  p += (size_t)NG * K_ * 2;  // 4 MB
  float*          biasP = (float*)p;           p += (size_t)NG * 4;       // 8 KB
  float*          c     = (float*)p;           p += (size_t)B_ * E_ * 4;  // 4 MB
  __hip_bfloat16* A0    = (__hip_bfloat16*)p;  p += (size_t)B_ * K_ * 2;  // 4 MB
  __hip_bfloat16* A1    = (__hip_bfloat16*)p;  p += (size_t)B_ * K_ * 2;  // 4 MB

  prep_weights<<<NG, 256, 0, stream>>>(Wih, Whh, bih, bhh, Wp, biasP);
  init_state<<<B_, 256, 0, stream>>>(x, emb, c, A0);
  for (int t = 0; t < S_; ++t) {
    __hip_bfloat16* Ac = (t & 1) ? A1 : A0;
    __hip_bfloat16* An = (t & 1) ? A0 : A1;
    lstm_step<<<512, 128, 0, stream>>>(Ac, An, Wp, biasP, c, x, emb, out, t);
  }
}